// Round 3
// baseline (400.299 us; speedup 1.0000x reference)
//
#include <hip/hip_runtime.h>

typedef __bf16 bf16x8 __attribute__((ext_vector_type(8)));
typedef float f32x4 __attribute__((ext_vector_type(4)));
typedef unsigned short u16;
typedef unsigned int u32;

#define SEQ 2048
#define NH 16
#define HD 64
#define DM 1024
#define NEG_BIG (-30000.0f)

__device__ __forceinline__ u16 f2bf(float f) {
  union { float f; u32 i; } x; x.f = f;
  u32 u = x.i;
  u += 0x7FFFu + ((u >> 16) & 1u);   // RNE
  return (u16)(u >> 16);
}
__device__ __forceinline__ f32x4 mfma16(bf16x8 a, bf16x8 b, f32x4 c) {
  return __builtin_amdgcn_mfma_f32_16x16x32_bf16(a, b, c, 0, 0, 0);
}

// ---- W f32 [K][N] -> Wt bf16 [N][K]; rows n < n_scale scaled by 0.125 ----
__global__ void transpose_w(const float* __restrict__ in, u16* __restrict__ out,
                            int K, int N, int n_scale)
{
  __shared__ float tile[32][33];
  int bn = blockIdx.x * 32, bk = blockIdx.y * 32;
  int tx = threadIdx.x, ty = threadIdx.y;
  #pragma unroll
  for (int i = ty; i < 32; i += 8)
    tile[i][tx] = in[(size_t)(bk + i) * N + bn + tx];
  __syncthreads();
  #pragma unroll
  for (int i = ty; i < 32; i += 8) {
    int n = bn + i;
    float v = tile[tx][i];
    if (n < n_scale) v *= 0.125f;
    out[(size_t)n * K + bk + tx] = f2bf(v);
  }
}

// ---- C = A[M][K] @ Bt[N][K]^T + bias.
//      A is f32 (Af) when a_is_f32, else bf16 (Ab). Bt always bf16.
//      mode 0: f32 row-major out; mode 1: bf16 QKV scatter ----
__global__ __launch_bounds__(256)
void gemm_bt(const float* __restrict__ Af, const u16* __restrict__ Ab,
             const u16* __restrict__ Bt, const float* __restrict__ bias,
             u16* __restrict__ Q, u16* __restrict__ Ko, u16* __restrict__ Vt,
             float* __restrict__ Cout,
             int N, int K, int mode, int a_is_f32)
{
  __shared__ __align__(16) u16 As[128 * 32];
  __shared__ __align__(16) u16 Bs[128 * 32];
  const int tid = threadIdx.x;
  const int wave = tid >> 6, lane = tid & 63;
  const int quad = lane >> 4, l16 = lane & 15;
  const int m0 = blockIdx.y * 128, n0 = blockIdx.x * 128;
  const int wr = (wave >> 1) * 64, wc = (wave & 1) * 64;
  const int sr = tid >> 2, sc = (tid & 3) * 8;   // staging: 8-elem chunk per thread

  const f32x4 fz = {0.f, 0.f, 0.f, 0.f};
  f32x4 acc[4][4];
  #pragma unroll
  for (int i = 0; i < 4; i++)
    #pragma unroll
    for (int j = 0; j < 4; j++) acc[i][j] = fz;

  const u16* b0 = Bt + (size_t)(n0 + sr) * K + sc;
  const u16* b1 = Bt + (size_t)(n0 + sr + 64) * K + sc;
  u16* as0 = As + sr * 32 + sc;
  u16* as1 = As + (sr + 64) * 32 + sc;
  u16* bs0 = Bs + sr * 32 + sc;
  u16* bs1 = Bs + (sr + 64) * 32 + sc;

  for (int k0 = 0; k0 < K; k0 += 32) {
    __syncthreads();
    if (a_is_f32) {
      const float* pa0 = Af + (size_t)(m0 + sr) * K + sc + k0;
      const float* pa1 = Af + (size_t)(m0 + sr + 64) * K + sc + k0;
      float4 x0 = *(const float4*)pa0, x1 = *(const float4*)(pa0 + 4);
      float4 y0 = *(const float4*)pa1, y1 = *(const float4*)(pa1 + 4);
      union { u16 h[8]; uint4 v; } u0, u1;
      u0.h[0] = f2bf(x0.x); u0.h[1] = f2bf(x0.y); u0.h[2] = f2bf(x0.z); u0.h[3] = f2bf(x0.w);
      u0.h[4] = f2bf(x1.x); u0.h[5] = f2bf(x1.y); u0.h[6] = f2bf(x1.z); u0.h[7] = f2bf(x1.w);
      u1.h[0] = f2bf(y0.x); u1.h[1] = f2bf(y0.y); u1.h[2] = f2bf(y0.z); u1.h[3] = f2bf(y0.w);
      u1.h[4] = f2bf(y1.x); u1.h[5] = f2bf(y1.y); u1.h[6] = f2bf(y1.z); u1.h[7] = f2bf(y1.w);
      *(uint4*)as0 = u0.v;
      *(uint4*)as1 = u1.v;
    } else {
      *(uint4*)as0 = *(const uint4*)(Ab + (size_t)(m0 + sr) * K + sc + k0);
      *(uint4*)as1 = *(const uint4*)(Ab + (size_t)(m0 + sr + 64) * K + sc + k0);
    }
    *(uint4*)bs0 = *(const uint4*)(b0 + k0);
    *(uint4*)bs1 = *(const uint4*)(b1 + k0);
    __syncthreads();
    bf16x8 af[4], bfr[4];
    #pragma unroll
    for (int i = 0; i < 4; i++)
      af[i] = *(const bf16x8*)(As + (wr + i * 16 + l16) * 32 + quad * 8);
    #pragma unroll
    for (int j = 0; j < 4; j++)
      bfr[j] = *(const bf16x8*)(Bs + (wc + j * 16 + l16) * 32 + quad * 8);
    #pragma unroll
    for (int i = 0; i < 4; i++)
      #pragma unroll
      for (int j = 0; j < 4; j++)
        acc[i][j] = mfma16(af[i], bfr[j], acc[i][j]);
  }

  // epilogue: C/D layout row = quad*4+r, col = l16 (m89-verified)
  #pragma unroll
  for (int j = 0; j < 4; j++) {
    int n = n0 + wc + j * 16 + l16;
    float bv = bias[n];
    if (mode == 1 && n < DM) bv *= 0.125f;   // Q part: fold 1/sqrt(hd)
    #pragma unroll
    for (int i = 0; i < 4; i++) {
      int mb = m0 + wr + i * 16 + quad * 4;
      #pragma unroll
      for (int r = 0; r < 4; r++) {
        int m = mb + r;
        float o = acc[i][j][r] + bv;
        if (mode == 0) {
          Cout[(size_t)m * N + n] = o;
        } else {
          u16 ob = f2bf(o);
          int which = n >> 10, f = n & (DM - 1);
          int h = f >> 6, d = f & (HD - 1);
          int b = m >> 11, t = m & (SEQ - 1);
          int bh = b * NH + h;
          if (which == 0)      Q[((size_t)bh * SEQ + t) * HD + d] = ob;
          else if (which == 1) Ko[((size_t)bh * SEQ + t) * HD + d] = ob;
          else                 Vt[((size_t)bh * HD + d) * SEQ + t] = ob;  // V transposed
        }
      }
    }
  }
}

// ---- causal flash attention: 1 wave = 16 q rows; K-tiles of 32 keys ----
__global__ __launch_bounds__(256)
void attn(const u16* __restrict__ Q, const u16* __restrict__ Kb,
          const u16* __restrict__ Vt, u16* __restrict__ Y)
{
  __shared__ __align__(16) u16 Pst[4 * 512];   // per-wave private 16x32 P tile
  const int tid = threadIdx.x;
  const int wave = tid >> 6, lane = tid & 63;
  const int quad = lane >> 4, l16 = lane & 15;
  const int blk = blockIdx.x;
  const int qb = blk & 31;          // T/64 = 32 q-blocks
  const int bh = blk >> 5;          // 0..31
  const int q0 = qb * 64 + wave * 16;
  const u16* Qp = Q + (size_t)bh * SEQ * HD;
  const u16* Kp = Kb + (size_t)bh * SEQ * HD;
  const u16* Vp = Vt + (size_t)bh * HD * SEQ;
  u16* Pw = Pst + wave * 512;

  // Q fragments (pre-scaled by 0.125 via W): A-layout, lane holds Q[q0+l16][quad*8+j]
  bf16x8 qa0 = *(const bf16x8*)(Qp + (q0 + l16) * HD + quad * 8);
  bf16x8 qa1 = *(const bf16x8*)(Qp + (q0 + l16) * HD + 32 + quad * 8);

  const f32x4 fz = {0.f, 0.f, 0.f, 0.f};
  f32x4 O[4];
  float mI[4], lI[4];
  #pragma unroll
  for (int c = 0; c < 4; c++) O[c] = fz;
  #pragma unroll
  for (int r = 0; r < 4; r++) { mI[r] = NEG_BIG; lI[r] = 0.f; }

  const int qmaxw = q0 + 15;
  for (int k0 = 0; k0 <= qmaxw; k0 += 32) {
    bf16x8 kf00 = *(const bf16x8*)(Kp + (k0 + l16) * HD + quad * 8);
    bf16x8 kf01 = *(const bf16x8*)(Kp + (k0 + l16) * HD + 32 + quad * 8);
    bf16x8 kf10 = *(const bf16x8*)(Kp + (k0 + 16 + l16) * HD + quad * 8);
    bf16x8 kf11 = *(const bf16x8*)(Kp + (k0 + 16 + l16) * HD + 32 + quad * 8);
    f32x4 S0 = fz, S1 = fz;
    S0 = mfma16(qa0, kf00, S0);
    S0 = mfma16(qa1, kf01, S0);
    S1 = mfma16(qa0, kf10, S1);
    S1 = mfma16(qa1, kf11, S1);

    if (k0 + 31 > q0) {              // diagonal tile: causal mask (key > query)
      #pragma unroll
      for (int r = 0; r < 4; r++) {
        int qg = q0 + quad * 4 + r;
        if (k0 + l16 > qg)      S0[r] = NEG_BIG;
        if (k0 + 16 + l16 > qg) S1[r] = NEG_BIG;
      }
    }

    // row max across 16 key-lanes (xor<16 stays within quad group)
    float mt[4];
    #pragma unroll
    for (int r = 0; r < 4; r++) mt[r] = fmaxf(S0[r], S1[r]);
    #pragma unroll
    for (int off = 1; off < 16; off <<= 1)
      #pragma unroll
      for (int r = 0; r < 4; r++) mt[r] = fmaxf(mt[r], __shfl_xor(mt[r], off, 64));

    float al[4], p0[4], p1[4], st[4];
    #pragma unroll
    for (int r = 0; r < 4; r++) {
      float mn = fmaxf(mI[r], mt[r]);
      al[r] = __expf(fminf(mI[r] - mn, 0.f));
      mI[r] = mn;
      p0[r] = __expf(fminf(S0[r] - mn, 0.f));
      p1[r] = __expf(fminf(S1[r] - mn, 0.f));
      st[r] = p0[r] + p1[r];
    }
    #pragma unroll
    for (int off = 1; off < 16; off <<= 1)
      #pragma unroll
      for (int r = 0; r < 4; r++) st[r] += __shfl_xor(st[r], off, 64);
    #pragma unroll
    for (int r = 0; r < 4; r++) lI[r] = lI[r] * al[r] + st[r];
    #pragma unroll
    for (int c = 0; c < 4; c++)
      #pragma unroll
      for (int r = 0; r < 4; r++) O[c][r] *= al[r];

    // P: C-layout -> LDS -> A-layout. Compiler fences order the TBAA-
    // incompatible u16 stores vs bf16x8 load; same-wave DS ops are in-order
    // in HW, and lgkmcnt covers the register dependency.
    #pragma unroll
    for (int r = 0; r < 4; r++) {
      int row = quad * 4 + r;
      Pw[row * 32 + l16]      = f2bf(p0[r]);
      Pw[row * 32 + 16 + l16] = f2bf(p1[r]);
    }
    asm volatile("" ::: "memory");
    bf16x8 pf = *(const bf16x8*)(Pw + l16 * 32 + quad * 8);
    asm volatile("" ::: "memory");
    #pragma unroll
    for (int c = 0; c < 4; c++) {
      bf16x8 vf = *(const bf16x8*)(Vp + (c * 16 + l16) * SEQ + k0 + quad * 8);
      O[c] = mfma16(pf, vf, O[c]);
    }
  }

  const int b = bh >> 4, h = bh & 15;
  #pragma unroll
  for (int r = 0; r < 4; r++) {
    float inv = 1.f / fmaxf(lI[r], 1e-30f);
    int t = q0 + quad * 4 + r;
    u16* yrow = Y + ((size_t)b * SEQ + t) * DM + h * HD;
    #pragma unroll
    for (int c = 0; c < 4; c++)
      yrow[c * 16 + l16] = f2bf(O[c][r] * inv);
  }
}

extern "C" void kernel_launch(void* const* d_in, const int* in_sizes, int n_in,
                              void* d_out, int out_size, void* d_ws, size_t ws_size,
                              hipStream_t stream)
{
  const float* x      = (const float*)d_in[0];   // f32 per reference
  const float* W_attn = (const float*)d_in[1];
  const float* b_attn = (const float*)d_in[2];
  const float* W_proj = (const float*)d_in[3];
  const float* b_proj = (const float*)d_in[4];
  float* out = (float*)d_out;                    // f32 per reference

  u16* ws = (u16*)d_ws;
  u16* Wt_attn = ws;                         // 3072*1024 bf16
  u16* Wt_proj = Wt_attn + 3072 * 1024;      // 1024*1024 bf16
  u16* Qb = Wt_proj + 1024 * 1024;           // 32*2048*64 bf16 each
  u16* Kb = Qb + 32 * 2048 * 64;
  u16* Vt = Kb + 32 * 2048 * 64;
  u16* Yb = Vt + 32 * 2048 * 64;

  transpose_w<<<dim3(3072 / 32, 1024 / 32), dim3(32, 8), 0, stream>>>(
      W_attn, Wt_attn, 1024, 3072, 1024);
  transpose_w<<<dim3(1024 / 32, 1024 / 32), dim3(32, 8), 0, stream>>>(
      W_proj, Wt_proj, 1024, 1024, 0);
  gemm_bt<<<dim3(3072 / 128, 4096 / 128), 256, 0, stream>>>(
      x, nullptr, Wt_attn, b_attn, Qb, Kb, Vt, nullptr, 3072, 1024, 1, 1);
  attn<<<dim3(32 * 32), 256, 0, stream>>>(Qb, Kb, Vt, Yb);
  gemm_bt<<<dim3(1024 / 128, 4096 / 128), 256, 0, stream>>>(
      nullptr, Yb, Wt_proj, b_proj, nullptr, nullptr, nullptr, out, 1024, 1024, 0, 0);
}